// Round 1
// baseline (723.299 us; speedup 1.0000x reference)
//
#include <hip/hip_runtime.h>
#include <cfloat>
#include <cmath>

#define TPB 256

typedef _Float16 half8 __attribute__((ext_vector_type(8)));
typedef float floatx16 __attribute__((ext_vector_type(16)));
typedef float floatx4 __attribute__((ext_vector_type(4)));
typedef float floatx2 __attribute__((ext_vector_type(2)));

__device__ __forceinline__ float wave_reduce_sum(float v) {
#pragma unroll
  for (int off = 32; off > 0; off >>= 1) v += __shfl_xor(v, off, 64);
  return v;
}

// ---------------------------------------------------------------------------
// Kernel 0a: encoder conv2 B-fragments (2-part f16 split).
// ---------------------------------------------------------------------------
__global__ __launch_bounds__(64) void prep_bfrags(
    const float* __restrict__ ce_w2, const float* __restrict__ ge_w2,
    float* __restrict__ frags) {
  const int blk = blockIdx.x;  // 144 = 2 enc x 72 frags
  const int enc = blk / 72;
  const int frag = blk % 72;
  const int ks = frag >> 2, part = (frag >> 1) & 1, nt = frag & 1;
  const int tap = ks >> 1, half = ks & 1;
  const int lane = threadIdx.x;
  const float* w2 = enc ? ge_w2 : ce_w2;
  const int n = nt * 32 + (lane & 31);
  const int cb = half * 16 + (lane >> 5) * 8;
  half8 out;
#pragma unroll
  for (int j = 0; j < 8; ++j) {
    float v = w2[(n * 32 + cb + j) * 9 + tap];
    _Float16 h = (_Float16)v;
    out[j] = (part == 0) ? h : (_Float16)((v - (float)h) * 4096.f);
  }
  *(half8*)((char*)frags + ((size_t)blk * 64 + lane) * 16) = out;
}

// ---------------------------------------------------------------------------
// Kernel 0b: decoder deconv1 B-fragments (single f16).
// ---------------------------------------------------------------------------
__global__ __launch_bounds__(64) void prep_dec1(
    const float* __restrict__ w1, float* __restrict__ frags) {
  const int blk = blockIdx.x;
  const int phase = blk >> 4, ks = blk & 15;
  const int pa = phase >> 1, pb = phase & 1;
  const int st = ks >> 2, kk = ks & 3;
  const int s = st >> 1, tt = st & 1;
  const int lane = threadIdx.x;
  const int kg = lane >> 5, n = lane & 31;
  const int tap = (pa + 2 * s) * 4 + (pb + 2 * tt);
  half8 o;
#pragma unroll
  for (int j = 0; j < 8; ++j) {
    int c = kk * 16 + kg * 8 + j;
    o[j] = (_Float16)w1[tap * 2048 + c * 32 + n];
  }
  *(half8*)((char*)frags + ((size_t)blk * 64 + lane) * 16) = o;
}

// ---------------------------------------------------------------------------
// Kernel 0c: decfc B-fragments (f16).
// ---------------------------------------------------------------------------
__global__ __launch_bounds__(64) void prep_dfc(
    const float* __restrict__ dfcw, float* __restrict__ frags) {
  const int blk = blockIdx.x;  // 784 = 98 nt x 8 ks
  const int nt = blk >> 3, ks = blk & 7;
  const int lane = threadIdx.x;
  const int n = lane & 31, kg = lane >> 5;
  const int j = nt * 32 + n;
  const int px = j >> 6, c = j & 63;
  half8 o;
#pragma unroll
  for (int u = 0; u < 8; ++u)
    o[u] = (_Float16)dfcw[(size_t)(c * 49 + px) * 128 + ks * 16 + kg * 8 + u];
  *(half8*)((char*)frags + ((size_t)blk * 64 + lane) * 16) = o;
}

// ---------------------------------------------------------------------------
// Kernel 0d: mem B-fragments for match (2-part f16 split).
// ---------------------------------------------------------------------------
__global__ __launch_bounds__(64) void prep_mem(
    const float* __restrict__ memg, float* __restrict__ frags) {
  const int blk = blockIdx.x;  // 4096 = 256 tiles x 16 slots
  const int slot = blk & 15;
  const int p = slot >> 3, ks = slot & 7;
  const int T = blk >> 4;
  const int lane = threadIdx.x;
  const int n = lane & 31, kg = lane >> 5;
  const float* src = memg + (size_t)(T * 32 + n) * 128 + ks * 16 + kg * 8;
  half8 o;
#pragma unroll
  for (int j = 0; j < 8; ++j) {
    float v = src[j];
    _Float16 h = (_Float16)v;
    o[j] = p ? (_Float16)((v - (float)h) * 4096.f) : h;
  }
  *(half8*)((char*)frags + ((size_t)blk * 64 + lane) * 16) = o;
}

// ---------------------------------------------------------------------------
// Kernel 1: memory row inverse norms
// ---------------------------------------------------------------------------
__global__ __launch_bounds__(256) void norm_kernel(
    const float* __restrict__ memg, float* __restrict__ invn) {
  const int wv = threadIdx.x >> 6, lane = threadIdx.x & 63;
  const int row = blockIdx.x * 4 + wv;
  const float* r = memg + (size_t)row * 128;
  float a = r[lane], b = r[lane + 64];
  float s = wave_reduce_sum(a * a + b * b);
  if (lane == 0) invn[row] = 1.f / fmaxf(sqrtf(s), 1e-12f);
}

// ---------------------------------------------------------------------------
// Kernel 2: MFMA encoder.
// v2: (M-tile, nt) work units for MFMA-phase load balance; wave-pinned
// channel group for staging with w1/b1 hoisted to wave-uniform registers;
// floatx2 packed conv1 FMAs.
// ---------------------------------------------------------------------------
template <int S, bool CENTER>
__device__ __forceinline__ void encoder_body(
    char* smem, const float* __restrict__ x, const float* __restrict__ w1,
    const float* __restrict__ b1, const float* __restrict__ b2,
    const float* __restrict__ fcw, const float* __restrict__ fcb,
    const float* __restrict__ bfrag, float* __restrict__ zout, int zoff,
    int b) {
  constexpr int SP = S + 2;
  constexpr int NBANDS = (S == 28) ? 3 : 2;
  constexpr int RMAX = 12;
  constexpr int NPIX = RMAX * SP;
  constexpr int GSTB = NPIX * 16;
  constexpr int PSTB = 4 * GSTB;

  char* h1s = smem;
  float* xs = (float*)(smem + 2 * PSTB);
  float* featp = xs + SP * SP;  // 128 floats

  const int t = threadIdx.x;
  const int lane = t & 63;
  const int wv = t >> 6;
  const int ntW = wv & 1;

  // hoist per-wave conv1 weights/bias (wave-uniform base -> scalar loads)
  const int gbase = __builtin_amdgcn_readfirstlane(wv * 8);
  floatx2 w1p[4][9];
  floatx2 b1p[4];
#pragma unroll
  for (int up = 0; up < 4; ++up) {
    b1p[up][0] = b1[gbase + 2 * up];
    b1p[up][1] = b1[gbase + 2 * up + 1];
#pragma unroll
    for (int v = 0; v < 9; ++v) {
      w1p[up][v][0] = w1[(gbase + 2 * up) * 9 + v];
      w1p[up][v][1] = w1[(gbase + 2 * up + 1) * 9 + v];
    }
  }

  for (int e = t; e < SP * SP; e += TPB) xs[e] = 0.f;
  __syncthreads();
  const float* xb = x + (size_t)b * 784 + (CENTER ? (7 * 28 + 7) : 0);
  for (int e = t; e < S * S; e += TPB) {
    int i = e / S, j = e - i * S;
    xs[(i + 1) * SP + (j + 1)] = xb[i * 28 + j];
  }

  float sp = 0.f;
  const float biasW = b2[ntW * 32 + (lane & 31)];
  const int gOff = (lane >> 5) * GSTB;
  const char* bgbase = (const char*)bfrag + lane * 16;

#pragma unroll
  for (int band = 0; band < NBANDS; ++band) {
    const int BH_ = (S == 28) ? ((band < 2) ? 10 : 8) : ((band == 0) ? 10 : 4);
    const int b0 = band * 10;
    const int LIMIT = BH_ * S;
    const int MTB = (LIMIT + 31) / 32;

    __syncthreads();
    // staging: wave wv handles channel group wv for all pixels
    for (int pix = lane; pix < NPIX; pix += 64) {
      int lr = pix / SP, cw = pix - lr * SP;
      int gr = b0 - 1 + lr;
      half8 hi8 = {}, lo8 = {};
      if (gr >= 0 && gr < S && cw >= 1 && cw <= S) {
        float xv[9];
#pragma unroll
        for (int di = 0; di < 3; ++di)
#pragma unroll
          for (int dj = 0; dj < 3; ++dj)
            xv[di * 3 + dj] = xs[(gr + di) * SP + (cw - 1 + dj)];
#pragma unroll
        for (int up = 0; up < 4; ++up) {
          floatx2 a2 = b1p[up];
#pragma unroll
          for (int v = 0; v < 9; ++v) a2 += xv[v] * w1p[up][v];
#pragma unroll
          for (int q = 0; q < 2; ++q) {
            float a = fmaxf(a2[q], 0.f);
            _Float16 h = (_Float16)a;
            hi8[2 * up + q] = h;
            lo8[2 * up + q] = (_Float16)((a - (float)h) * 4096.f);
          }
        }
      }
      const int ebase = wv * GSTB + pix * 16;
      *(half8*)(h1s + ebase) = hi8;
      *(half8*)(h1s + PSTB + ebase) = lo8;
    }
    __syncthreads();
    // MFMA: unit = (single M-tile, single nt); wave parity pins nt
#pragma unroll 1
    for (int u = wv; u < 2 * MTB; u += 4) {
      const int mt = u >> 1;
      floatx16 accH = {}, accL = {};
      int px = mt * 32 + (lane & 31);
      px = px < LIMIT ? px : LIMIT - 1;
      const int r = px / S, cc = px - r * S;
      const int pixB = (r * SP + cc) * 16;
#pragma unroll
      for (int tap = 0; tap < 9; ++tap) {
        const int di = tap / 3, dj = tap - di * 3;
        const int offT = (di * SP + dj) * 16;
#pragma unroll
        for (int half = 0; half < 2; ++half) {
          const int ks = tap * 2 + half;
          const char* bp = bgbase + ks * 4096 + ntW * 1024;
          const int offA = pixB + offT + gOff + half * (2 * GSTB);
          half8 ah = *(const half8*)(h1s + offA);
          half8 al = *(const half8*)(h1s + PSTB + offA);
          half8 bh = *(const half8*)(bp);
          half8 bl = *(const half8*)(bp + 2048);
          accH = __builtin_amdgcn_mfma_f32_32x32x16_f16(ah, bh, accH, 0, 0, 0);
          accL = __builtin_amdgcn_mfma_f32_32x32x16_f16(ah, bl, accL, 0, 0, 0);
          accL = __builtin_amdgcn_mfma_f32_32x32x16_f16(al, bh, accL, 0, 0, 0);
        }
      }
#pragma unroll
      for (int reg = 0; reg < 16; ++reg) {
        int row = (reg & 3) + 8 * (reg >> 2) + 4 * (lane >> 5);
        int p = mt * 32 + row;
        if (p < LIMIT)
          sp += fmaxf(accH[reg] + accL[reg] * (1.f / 4096.f) + biasW, 0.f);
      }
    }
  }
  sp += __shfl_xor(sp, 32);
  if (lane < 32) featp[wv * 32 + lane] = sp;
  __syncthreads();
  if (t < 64) featp[t] = (featp[t] + featp[64 + t]) * (1.f / (S * S));
  __syncthreads();
  if (t < 64) {
    float s = 0.f;
#pragma unroll
    for (int i = 0; i < 64; ++i) s += featp[i] * fcw[t * 64 + i];
    zout[(size_t)b * 128 + zoff + t] = s + fcb[t];
  }
}

__global__ __launch_bounds__(256, 3) void encoders_fused(
    const float* __restrict__ x, const float* __restrict__ ce_w1,
    const float* __restrict__ ce_b1, const float* __restrict__ ce_b2,
    const float* __restrict__ ce_fcw, const float* __restrict__ ce_fcb,
    const float* __restrict__ ge_w1, const float* __restrict__ ge_b1,
    const float* __restrict__ ge_b2, const float* __restrict__ ge_fcw,
    const float* __restrict__ ge_fcb, const float* __restrict__ frags,
    float* __restrict__ z) {
  // S=28: 2*PSTB(46080) + xs(3600) + featp(512) = 50192
  __shared__ __align__(16) char smem[50192];
  if (blockIdx.x < 2048)
    encoder_body<28, false>(smem, x, ge_w1, ge_b1, ge_b2, ge_fcw, ge_fcb,
                            frags + 18432, z, 64, blockIdx.x);
  else
    encoder_body<14, true>(smem, x, ce_w1, ce_b1, ce_b2, ce_fcw, ce_fcb, frags,
                           z, 0, blockIdx.x - 2048);
}

// ---------------------------------------------------------------------------
// Kernel 3a: match via split-f16 MFMA.
// ---------------------------------------------------------------------------
__global__ __launch_bounds__(256) void match_mfma(
    const float* __restrict__ z, const float* __restrict__ memfrags,
    const float* __restrict__ invn, float* __restrict__ topvw,
    int* __restrict__ topiw) {
  __shared__ __align__(16) char smem[49408];
  float* zs = (float*)smem;            // [32][128] fp32 (staging)
  float* qv = (float*)smem;            // [32][128] (after zs dead)
  int* qi = (int*)(smem + 16384);      // [32][128]
  char* zfrag = smem + 32768;          // 16 KB: [p][ks][kg*32+m][16B]
  float* rowmin = (float*)(smem + 49152);
  int* qn = (int*)(smem + 49152 + 128);

  const int t = threadIdx.x;
  const int lane = t & 63;
  const int wv = t >> 6;
  const int rowbase = blockIdx.x * 32;
  const int Tbase = blockIdx.y * 16;

  for (int e = t; e < 4096; e += TPB) zs[e] = z[(size_t)rowbase * 128 + e];
  if (t < 32) { rowmin[t] = -FLT_MAX; qn[t] = 0; }
  __syncthreads();
#pragma unroll
  for (int h = 0; h < 8; ++h) {
    int r = wv * 8 + h;
    float a = zs[r * 128 + lane], b = zs[r * 128 + 64 + lane];
    float s = wave_reduce_sum(a * a + b * b);
    float inv = 1.f / fmaxf(sqrtf(s), 1e-12f);
    zs[r * 128 + lane] = a * inv;
    zs[r * 128 + 64 + lane] = b * inv;
  }
  __syncthreads();
  // build z A-fragments (2-part split), frag-major: entry (ks*64+kg*32+m)
  for (int e = t; e < 4096; e += TPB) {
    int m = e >> 7, c = e & 127;
    float v = zs[m * 128 + c];
    _Float16 h = (_Float16)v;
    _Float16 l = (_Float16)((v - (float)h) * 4096.f);
    int ks = c >> 4, kg = (c >> 3) & 1, j = c & 7;
    int off = (ks * 64 + kg * 32 + m) * 16 + j * 2;
    *(_Float16*)(zfrag + off) = h;
    *(_Float16*)(zfrag + 8192 + off) = l;
  }
  __syncthreads();

  // hoist A-fragments to registers (constant across all 16 n-tiles)
  half8 ah[8], al[8];
  {
    const char* zf = zfrag + ((lane >> 5) * 32 + (lane & 31)) * 16;
#pragma unroll
    for (int ks = 0; ks < 8; ++ks) {
      ah[ks] = *(const half8*)(zf + ks * 1024);
      al[ks] = *(const half8*)(zf + 8192 + ks * 1024);
    }
  }

  float av[10];
  int ai[10];
#pragma unroll
  for (int i = 0; i < 10; ++i) { av[i] = -FLT_MAX; ai[i] = 0; }

#pragma unroll 1
  for (int round = 0; round < 4; ++round) {
    const int T = Tbase + round * 4 + wv;
    const char* bf = (const char*)memfrags + (size_t)T * 16384 + lane * 16;
    floatx16 acc0 = {}, acc1 = {};
#pragma unroll
    for (int ks = 0; ks < 8; ++ks) {
      half8 bh = *(const half8*)(bf + ks * 1024);
      half8 bl = *(const half8*)(bf + 8192 + ks * 1024);
      acc0 = __builtin_amdgcn_mfma_f32_32x32x16_f16(ah[ks], bh, acc0, 0, 0, 0);
      acc1 = __builtin_amdgcn_mfma_f32_32x32x16_f16(ah[ks], bl, acc1, 0, 0, 0);
      acc1 = __builtin_amdgcn_mfma_f32_32x32x16_f16(al[ks], bh, acc1, 0, 0, 0);
    }
    const int gn = T * 32 + (lane & 31);
    const float iv = invn[gn];
#pragma unroll
    for (int reg = 0; reg < 16; ++reg) {
      int m = (reg & 3) + 8 * (reg >> 2) + 4 * (lane >> 5);
      float v = (acc0[reg] + acc1[reg] * (1.f / 4096.f)) * iv;
      if (v > rowmin[m]) {
        int k = atomicAdd(&qn[m], 1);
        qv[m * 128 + k] = v;
        qi[m * 128 + k] = gn;
      }
    }
    __syncthreads();
    if (t < 32) {
      int n = qn[t];
      for (int k = 0; k < n; ++k) {
        float v = qv[t * 128 + k];
        int mm = qi[t * 128 + k];
        if (v > av[9]) {
#pragma unroll
          for (int i = 0; i < 10; ++i) {
            if (v > av[i]) {
              float tv = av[i]; av[i] = v; v = tv;
              int ti = ai[i]; ai[i] = mm; mm = ti;
            }
          }
        }
      }
      qn[t] = 0;
      rowmin[t] = av[9];
    }
    __syncthreads();
  }

  if (t < 32) {
    const size_t base = (size_t)(rowbase + t) * 160 + blockIdx.y * 10;
#pragma unroll
    for (int k = 0; k < 10; ++k) {
      topvw[base + k] = av[k];
      topiw[base + k] = ai[k];
    }
  }
}

// ---------------------------------------------------------------------------
// Kernel 3b: merge 16x10 candidates -> exact top-10 -> softmax -> blend (f16).
// ---------------------------------------------------------------------------
__global__ __launch_bounds__(256) void match_merge(
    const float* __restrict__ topvw, const int* __restrict__ topiw,
    const float* __restrict__ memg, _Float16* __restrict__ zmf16) {
  __shared__ float topw[8][10];
  __shared__ int topidx[8][10];
  const int t = threadIdx.x;
  const int rowbase = blockIdx.x * 8;

  if (t < 8) {
    float av[10];
    int ai[10];
#pragma unroll
    for (int i = 0; i < 10; ++i) { av[i] = -FLT_MAX; ai[i] = 0; }
    const size_t base = (size_t)(rowbase + t) * 160;
    for (int c = 0; c < 160; ++c) {
      float v = topvw[base + c];
      int m = topiw[base + c];
      if (v > av[9]) {
#pragma unroll
        for (int i = 0; i < 10; ++i) {
          if (v > av[i]) {
            float tv = av[i]; av[i] = v; v = tv;
            int ti = ai[i]; ai[i] = m; m = ti;
          }
        }
      }
    }
    float e_[10], s = 0.f;
#pragma unroll
    for (int k = 0; k < 10; ++k) { e_[k] = expf(av[k]); s += e_[k]; }
    float inv = 1.f / s;
#pragma unroll
    for (int k = 0; k < 10; ++k) { topw[t][k] = e_[k] * inv; topidx[t][k] = ai[k]; }
  }
  __syncthreads();
  for (int e = t; e < 8 * 128; e += TPB) {
    int r = e >> 7, d = e & 127;
    float o = 0.f;
#pragma unroll
    for (int k = 0; k < 10; ++k)
      o += topw[r][k] * memg[(size_t)topidx[r][k] * 128 + d];
    zmf16[(size_t)(rowbase + r) * 128 + d] = (_Float16)o;
  }
}

// ---------------------------------------------------------------------------
// Kernel 4: decoder FC via f16 MFMA.
// ---------------------------------------------------------------------------
__global__ __launch_bounds__(256) void decfc_kernel(
    const _Float16* __restrict__ zmf16, const float* __restrict__ fcb,
    const float* __restrict__ dfcfrags, _Float16* __restrict__ d0f16) {
  const int t = threadIdx.x;
  const int lane = t & 63;
  const int wv = t >> 6;
  const int r0 = blockIdx.x * 32;
  const int ntbase = blockIdx.y * 49;

  half8 a[8];
  {
    const _Float16* ap =
        zmf16 + (size_t)(r0 + (lane & 31)) * 128 + (lane >> 5) * 8;
#pragma unroll
    for (int ks = 0; ks < 8; ++ks) a[ks] = *(const half8*)(ap + ks * 16);
  }
  const char* fb = (const char*)dfcfrags + lane * 16;

  for (int nt = ntbase + wv; nt < ntbase + 49; nt += 4) {
    half8 bfr[8];
    const char* p = fb + (size_t)nt * 8192;
#pragma unroll
    for (int ks = 0; ks < 8; ++ks) bfr[ks] = *(const half8*)(p + ks * 1024);
    floatx16 acc = {};
#pragma unroll
    for (int ks = 0; ks < 8; ++ks)
      acc = __builtin_amdgcn_mfma_f32_32x32x16_f16(a[ks], bfr[ks], acc, 0, 0, 0);
    const int col = nt * 32 + (lane & 31);
    const int px = col >> 6, c = col & 63;
    const float bias = fcb[c * 49 + px];
#pragma unroll
    for (int reg = 0; reg < 16; ++reg) {
      int row = (reg & 3) + 8 * (reg >> 2) + 4 * (lane >> 5);
      d0f16[((size_t)(r0 + row) * 49 + px) * 64 + c] = (_Float16)(acc[reg] + bias);
    }
  }
}

// ---------------------------------------------------------------------------
// Kernel 5: decoder v4 — deconv1 + conv2 via f16 MFMA.
// ---------------------------------------------------------------------------
__global__ __launch_bounds__(256) void decoder_kernel(
    const _Float16* __restrict__ d0f16, const float* __restrict__ b1,
    const float* __restrict__ w2, const float* __restrict__ b2,
    const float* __restrict__ w3, const float* __restrict__ b3,
    const float* __restrict__ w4, const float* __restrict__ b4,
    const float* __restrict__ dec1frags, float* __restrict__ out) {
  __shared__ __align__(16) char dsm[41408];
  char* d0f = dsm;
  float* d2 = (float*)dsm;
  char* d1f = dsm + 12608;
  char* w2s = dsm + 28992;
  float* d3 = (float*)(dsm + 12608);

  const int b = blockIdx.x;
  const int t = threadIdx.x;
  const int lane = t & 63;
  const int wv = t >> 6;

  for (int e = t; e < 648; e += TPB) {
    int g = e / 81, pix = e - g * 81;
    int ih = pix / 9 - 1, iw = pix % 9 - 1;
    half8 hv = {};
    if (ih >= 0 && ih < 7 && iw >= 0 && iw < 7)
      hv = *(const half8*)(d0f16 + ((size_t)b * 49 + ih * 7 + iw) * 64 + g * 8);
    *(half8*)(d0f + e * 16) = hv;
  }
  for (int e = t; e < 576; e += TPB) {
    int tau = e / 64, l = e - tau * 64;
    int n = l & 15, kq = l >> 4;
    half8 v;
#pragma unroll
    for (int u = 0; u < 8; ++u)
      v[u] = (_Float16)w2[(n * 32 + kq * 8 + u) * 9 + tau];
    *(half8*)(w2s + e * 16) = v;
  }
  for (int e = t; e < 1024; e += TPB)
    *(float4*)(d1f + e * 16) = make_float4(0.f, 0.f, 0.f, 0.f);
  __syncthreads();

  {
    const int pa = wv >> 1, pb = wv & 1;
    const int kg = lane >> 5, o = lane & 31;
    const char* bg = (const char*)dec1frags + wv * 16384 + lane * 16;
    int pxa[2][4];
#pragma unroll
    for (int im = 0; im < 2; ++im) {
      int px = im * 32 + o;
      px = px < 49 ? px : 48;
      int i = px / 7, j2 = px - i * 7;
#pragma unroll
      for (int st = 0; st < 4; ++st) {
        int s = st >> 1, tt = st & 1;
        pxa[im][st] = ((i + pa + s) * 9 + (j2 + pb + tt)) * 16;
      }
    }
    floatx16 acc0 = {}, acc1 = {};
    half8 nb = *(const half8*)(bg);
#pragma unroll
    for (int ks = 0; ks < 16; ++ks) {
      half8 bf = nb;
      if (ks < 15) nb = *(const half8*)(bg + (ks + 1) * 1024);
      const int gbase = (((ks & 3) * 2 + kg) * 81) * 16;
      half8 a0 = *(const half8*)(d0f + gbase + pxa[0][ks >> 2]);
      half8 a1 = *(const half8*)(d0f + gbase + pxa[1][ks >> 2]);
      acc0 = __builtin_amdgcn_mfma_f32_32x32x16_f16(a0, bf, acc0, 0, 0, 0);
      acc1 = __builtin_amdgcn_mfma_f32_32x32x16_f16(a1, bf, acc1, 0, 0, 0);
    }
    const float bias = b1[o];
    char* dst = d1f + (o >> 3) * 4096 + (o & 7) * 2;
#pragma unroll
    for (int im = 0; im < 2; ++im) {
      const floatx16& ac = im ? acc1 : acc0;
#pragma unroll
      for (int reg = 0; reg < 16; ++reg) {
        int row = (reg & 3) + 8 * (reg >> 2) + 4 * kg;
        int px = im * 32 + row;
        if (px < 49) {
          int i = px / 7, j2 = px - i * 7;
          int p = 2 * i + pa, q = 2 * j2 + pb;
          *(_Float16*)(dst + ((p + 1) * 16 + (q + 1)) * 16) =
              (_Float16)fmaxf(ac[reg] + bias, 0.f);
        }
      }
    }
  }
  __syncthreads();

  {
    const int m = lane & 15, kq = lane >> 4;
    half8 bq[9];
#pragma unroll
    for (int tau = 0; tau < 9; ++tau)
      bq[tau] = *(const half8*)(w2s + (tau * 64 + lane) * 16);
    for (int mt = wv; mt < 13; mt += 4) {
      int px = mt * 16 + m;
      px = px < 196 ? px : 195;
      const int p = px / 14, q = px - (px / 14) * 14;
      floatx4 acc = {};
#pragma unroll
      for (int tau = 0; tau < 9; ++tau) {
        const int dp = tau / 3, dq = tau - dp * 3;
        half8 av =
            *(const half8*)(d1f + (kq * 256 + (p + dp) * 16 + (q + dq)) * 16);
        acc = __builtin_amdgcn_mfma_f32_16x16x32_f16(av, bq[tau], acc, 0, 0, 0);
      }
      const int o = lane & 15;
      const float bias = b2[o];
#pragma unroll
      for (int reg = 0; reg < 4; ++reg) {
        int row = (lane >> 4) * 4 + reg;
        int opx = mt * 16 + row;
        if (opx < 196) d2[o * 197 + opx] = fmaxf(acc[reg] + bias, 0.f);
      }
    }
  }
  __syncthreads();
  for (int e = t; e < 7200; e += TPB) d3[e] = 0.f;
  __syncthreads();

  {
    const int ph = __builtin_amdgcn_readfirstlane(t >> 6);
    const int pa = ph >> 1, pb = ph & 1;
    const int tb = pa * 4 + pb;
    const float* wA = w3 + (size_t)tb * 128;
    const float* wB = w3 + (size_t)(tb + 2) * 128;
    const float* wC = w3 + (size_t)(tb + 8) * 128;
    const float* wD = w3 + (size_t)(tb + 10) * 128;
#pragma unroll 1
    for (int k = 0; k < 4; ++k) {
      const int px = lane + 64 * k;
      const int cpx = px < 196 ? px : 195;
      const int i = cpx / 14, j = cpx % 14;
      int ih[2], iw[2];
      float mh[2], mw[2];
#pragma unroll
      for (int s = 0; s < 2; ++s) {
        int v = i + pa + s - 1;
        mh[s] = (v >= 0 && v <= 13) ? 1.f : 0.f;
        ih[s] = v < 0 ? 0 : (v > 13 ? 13 : v);
        int u = j + pb + s - 1;
        mw[s] = (u >= 0 && u <= 13) ? 1.f : 0.f;
        iw[s] = u < 0 ? 0 : (u > 13 ? 13 : u);
      }
      const float m00 = mh[0] * mw[0], m01 = mh[0] * mw[1];
      const float m10 = mh[1] * mw[0], m11 = mh[1] * mw[1];
      float acc[8];
#pragma unroll
      for (int oo = 0; oo < 8; ++oo) acc[oo] = b3[oo];
#pragma unroll 2
      for (int c = 0; c < 16; ++c) {
        const float a00 = d2[c * 197 + ih[0] * 14 + iw[0]] * m00;
        const float a01 = d2[c * 197 + ih[0] * 14 + iw[1]] * m01;
        const float a10 = d2[c * 197 + ih[1] * 14 + iw[0]] * m10;
        const float a11 = d2[c * 197 + ih[1] * 14 + iw[1]] * m11;
        const int wb = c * 8;
#pragma unroll
        for (int oo = 0; oo < 8; ++oo)
          acc[oo] += a00 * wA[wb + oo] + a01 * wB[wb + oo] +
                     a10 * wC[wb + oo] + a11 * wD[wb + oo];
      }
      if (px < 196) {
        const int p = 2 * i + pa, q = 2 * j + pb;
        const int widx = (p + 1) * 30 + (q + 1);
#pragma unroll
        for (int oo = 0; oo < 8; ++oo)
          d3[oo * 900 + widx] = fmaxf(acc[oo], 0.f);
      }
    }
  }
  __syncthreads();

  for (int e = t; e < 784; e += TPB) {
    int p = e / 28, q = e - p * 28;
    float a = b4[0];
#pragma unroll
    for (int c = 0; c < 8; ++c) {
      const float* bp = &d3[c * 900 + p * 30 + q];
#pragma unroll
      for (int di = 0; di < 3; ++di)
#pragma unroll
        for (int dj = 0; dj < 3; ++dj)
          a += bp[di * 30 + dj] * w4[c * 9 + di * 3 + dj];
    }
    out[(size_t)b * 784 + e] = a;
  }
}

// ---------------------------------------------------------------------------
extern "C" void kernel_launch(void* const* d_in, const int* in_sizes, int n_in,
                              void* d_out, int out_size, void* d_ws,
                              size_t ws_size, hipStream_t stream) {
  const float* x      = (const float*)d_in[0];
  const float* ce_w1  = (const float*)d_in[1];
  const float* ce_b1  = (const float*)d_in[2];
  const float* ce_w2  = (const float*)d_in[3];
  const float* ce_b2  = (const float*)d_in[4];
  const float* ce_fcw = (const float*)d_in[5];
  const float* ce_fcb = (const float*)d_in[6];
  const float* ge_w1  = (const float*)d_in[7];
  const float* ge_b1  = (const float*)d_in[8];
  const float* ge_w2  = (const float*)d_in[9];
  const float* ge_b2  = (const float*)d_in[10];
  const float* ge_fcw = (const float*)d_in[11];
  const float* ge_fcb = (const float*)d_in[12];
  const float* memg   = (const float*)d_in[13];
  const float* dfcw   = (const float*)d_in[14];
  const float* dfcb   = (const float*)d_in[15];
  const float* d_w1   = (const float*)d_in[16];
  const float* d_b1   = (const float*)d_in[17];
  const float* d_w2   = (const float*)d_in[18];
  const float* d_b2   = (const float*)d_in[19];
  const float* d_w3   = (const float*)d_in[20];
  const float* d_b3   = (const float*)d_in[21];
  const float* d_w4   = (const float*)d_in[22];
  const float* d_b4   = (const float*)d_in[23];
  float* outp = (float*)d_out;

  float*     ws        = (float*)d_ws;
  float*     z         = ws;
  _Float16*  zmf16     = (_Float16*)(ws + 262144);
  float*     invn      = ws + 262144 + 131072;
  float*     frags     = invn + 8192;
  float*     dec1frags = frags + 36864;
  float*     dfcfrags  = dec1frags + 16384;
  float*     memfrags  = dfcfrags + 200704;
  float*     tailbase  = memfrags + 1048576;
  float*     topvw     = tailbase;
  int*       topiw     = (int*)(tailbase + 327680);
  _Float16*  d0f16     = (_Float16*)tailbase;

  prep_bfrags<<<144, 64, 0, stream>>>(ce_w2, ge_w2, frags);
  prep_dec1<<<64, 64, 0, stream>>>(d_w1, dec1frags);
  prep_dfc<<<784, 64, 0, stream>>>(dfcw, dfcfrags);
  prep_mem<<<4096, 64, 0, stream>>>(memg, memfrags);
  norm_kernel<<<2048, TPB, 0, stream>>>(memg, invn);
  encoders_fused<<<4096, TPB, 0, stream>>>(x, ce_w1, ce_b1, ce_b2, ce_fcw,
                                           ce_fcb, ge_w1, ge_b1, ge_b2, ge_fcw,
                                           ge_fcb, frags, z);
  match_mfma<<<dim3(64, 16), TPB, 0, stream>>>(z, memfrags, invn, topvw, topiw);
  match_merge<<<256, TPB, 0, stream>>>(topvw, topiw, memg, zmf16);
  decfc_kernel<<<dim3(64, 2), TPB, 0, stream>>>(zmf16, dfcb, dfcfrags, d0f16);
  decoder_kernel<<<2048, TPB, 0, stream>>>(d0f16, d_b1, d_w2, d_b2, d_w3, d_b3,
                                           d_w4, d_b4, dec1frags, outp);
}

// Round 2
// 661.334 us; speedup vs baseline: 1.0937x; 1.0937x over previous
//
#include <hip/hip_runtime.h>
#include <cfloat>
#include <cmath>

#define TPB 256

typedef _Float16 half8 __attribute__((ext_vector_type(8)));
typedef float floatx16 __attribute__((ext_vector_type(16)));
typedef float floatx4 __attribute__((ext_vector_type(4)));

__device__ __forceinline__ float wave_reduce_sum(float v) {
#pragma unroll
  for (int off = 32; off > 0; off >>= 1) v += __shfl_xor(v, off, 64);
  return v;
}

// ---------------------------------------------------------------------------
// Kernel 0a: encoder conv2 B-fragments (2-part f16 split).
// ---------------------------------------------------------------------------
__global__ __launch_bounds__(64) void prep_bfrags(
    const float* __restrict__ ce_w2, const float* __restrict__ ge_w2,
    float* __restrict__ frags) {
  const int blk = blockIdx.x;  // 144 = 2 enc x 72 frags
  const int enc = blk / 72;
  const int frag = blk % 72;
  const int ks = frag >> 2, part = (frag >> 1) & 1, nt = frag & 1;
  const int tap = ks >> 1, half = ks & 1;
  const int lane = threadIdx.x;
  const float* w2 = enc ? ge_w2 : ce_w2;
  const int n = nt * 32 + (lane & 31);
  const int cb = half * 16 + (lane >> 5) * 8;
  half8 out;
#pragma unroll
  for (int j = 0; j < 8; ++j) {
    float v = w2[(n * 32 + cb + j) * 9 + tap];
    _Float16 h = (_Float16)v;
    out[j] = (part == 0) ? h : (_Float16)((v - (float)h) * 4096.f);
  }
  *(half8*)((char*)frags + ((size_t)blk * 64 + lane) * 16) = out;
}

// ---------------------------------------------------------------------------
// Kernel 0b: decoder deconv1 B-fragments (single f16).
// ---------------------------------------------------------------------------
__global__ __launch_bounds__(64) void prep_dec1(
    const float* __restrict__ w1, float* __restrict__ frags) {
  const int blk = blockIdx.x;
  const int phase = blk >> 4, ks = blk & 15;
  const int pa = phase >> 1, pb = phase & 1;
  const int st = ks >> 2, kk = ks & 3;
  const int s = st >> 1, tt = st & 1;
  const int lane = threadIdx.x;
  const int kg = lane >> 5, n = lane & 31;
  const int tap = (pa + 2 * s) * 4 + (pb + 2 * tt);
  half8 o;
#pragma unroll
  for (int j = 0; j < 8; ++j) {
    int c = kk * 16 + kg * 8 + j;
    o[j] = (_Float16)w1[tap * 2048 + c * 32 + n];
  }
  *(half8*)((char*)frags + ((size_t)blk * 64 + lane) * 16) = o;
}

// ---------------------------------------------------------------------------
// Kernel 0c: decfc B-fragments (f16).
// ---------------------------------------------------------------------------
__global__ __launch_bounds__(64) void prep_dfc(
    const float* __restrict__ dfcw, float* __restrict__ frags) {
  const int blk = blockIdx.x;  // 784 = 98 nt x 8 ks
  const int nt = blk >> 3, ks = blk & 7;
  const int lane = threadIdx.x;
  const int n = lane & 31, kg = lane >> 5;
  const int j = nt * 32 + n;
  const int px = j >> 6, c = j & 63;
  half8 o;
#pragma unroll
  for (int u = 0; u < 8; ++u)
    o[u] = (_Float16)dfcw[(size_t)(c * 49 + px) * 128 + ks * 16 + kg * 8 + u];
  *(half8*)((char*)frags + ((size_t)blk * 64 + lane) * 16) = o;
}

// ---------------------------------------------------------------------------
// Kernel 0d: mem B-fragments for match (2-part f16 split).
// ---------------------------------------------------------------------------
__global__ __launch_bounds__(64) void prep_mem(
    const float* __restrict__ memg, float* __restrict__ frags) {
  const int blk = blockIdx.x;  // 4096 = 256 tiles x 16 slots
  const int slot = blk & 15;
  const int p = slot >> 3, ks = slot & 7;
  const int T = blk >> 4;
  const int lane = threadIdx.x;
  const int n = lane & 31, kg = lane >> 5;
  const float* src = memg + (size_t)(T * 32 + n) * 128 + ks * 16 + kg * 8;
  half8 o;
#pragma unroll
  for (int j = 0; j < 8; ++j) {
    float v = src[j];
    _Float16 h = (_Float16)v;
    o[j] = p ? (_Float16)((v - (float)h) * 4096.f) : h;
  }
  *(half8*)((char*)frags + ((size_t)blk * 64 + lane) * 16) = o;
}

// ---------------------------------------------------------------------------
// Kernel 1: memory row inverse norms
// ---------------------------------------------------------------------------
__global__ __launch_bounds__(256) void norm_kernel(
    const float* __restrict__ memg, float* __restrict__ invn) {
  const int wv = threadIdx.x >> 6, lane = threadIdx.x & 63;
  const int row = blockIdx.x * 4 + wv;
  const float* r = memg + (size_t)row * 128;
  float a = r[lane], b = r[lane + 64];
  float s = wave_reduce_sum(a * a + b * b);
  if (lane == 0) invn[row] = 1.f / fmaxf(sqrtf(s), 1e-12f);
}

// ---------------------------------------------------------------------------
// Kernel 2: MFMA encoder.
// v3: staging identical to the proven 319us version (w1s broadcast from LDS
// — zero register cost, LDS same-address broadcast is free). MFMA phase
// rebalanced: work unit = (single M-tile, single nt), wave parity pins nt.
// Critical path 1080 -> 756 MFMA-units (global), 432 -> 216 (center).
// Accumulator 2x floatx16 (was 8x).
// ---------------------------------------------------------------------------
template <int S, bool CENTER>
__device__ __forceinline__ void encoder_body(
    char* smem, const float* __restrict__ x, const float* __restrict__ w1,
    const float* __restrict__ b1, const float* __restrict__ b2,
    const float* __restrict__ fcw, const float* __restrict__ fcb,
    const float* __restrict__ bfrag, float* __restrict__ zout, int zoff,
    int b) {
  constexpr int SP = S + 2;
  constexpr int NBANDS = (S == 28) ? 3 : 2;
  constexpr int RMAX = 12;
  constexpr int NPIX = RMAX * SP;
  constexpr int GSTB = NPIX * 16;
  constexpr int PSTB = 4 * GSTB;

  char* h1s = smem;
  float* xs = (float*)(smem + 2 * PSTB);
  float* w1s = xs + SP * SP;
  float* featp = w1s + 288;  // [4][32]

  const int t = threadIdx.x;
  const int lane = t & 63;
  const int wv = t >> 6;
  const int ntW = wv & 1;

  for (int e = t; e < SP * SP; e += TPB) xs[e] = 0.f;
  for (int e = t; e < 288; e += TPB) w1s[e] = w1[e];
  __syncthreads();
  const float* xb = x + (size_t)b * 784 + (CENTER ? (7 * 28 + 7) : 0);
  for (int e = t; e < S * S; e += TPB) {
    int i = e / S, j = e - i * S;
    xs[(i + 1) * SP + (j + 1)] = xb[i * 28 + j];
  }

  float sp = 0.f;
  const float biasW = b2[ntW * 32 + (lane & 31)];
  const int gOff = (lane >> 5) * GSTB;
  const char* bgbase = (const char*)bfrag + lane * 16;

#pragma unroll
  for (int band = 0; band < NBANDS; ++band) {
    const int BH_ = (S == 28) ? ((band < 2) ? 10 : 8) : ((band == 0) ? 10 : 4);
    const int b0 = band * 10;
    const int LIMIT = BH_ * S;
    const int MTB = (LIMIT + 31) / 32;

    __syncthreads();
    for (int e = t; e < 4 * NPIX; e += TPB) {
      int g = e / NPIX;
      int pix = e - g * NPIX;
      int lr = pix / SP;
      int cw = pix - lr * SP;
      int gr = b0 - 1 + lr;
      int ebase = g * GSTB + pix * 16;
      half8 hi8 = {}, lo8 = {};
      if (gr >= 0 && gr < S && cw >= 1 && cw <= S) {
        float xv[9];
#pragma unroll
        for (int di = 0; di < 3; ++di)
#pragma unroll
          for (int dj = 0; dj < 3; ++dj)
            xv[di * 3 + dj] = xs[(gr + di) * SP + (cw - 1 + dj)];
#pragma unroll
        for (int u = 0; u < 8; ++u) {
          int ch = g * 8 + u;
          float a = b1[ch];
#pragma unroll
          for (int v = 0; v < 9; ++v) a += xv[v] * w1s[ch * 9 + v];
          a = fmaxf(a, 0.f);
          _Float16 h = (_Float16)a;
          hi8[u] = h;
          lo8[u] = (_Float16)((a - (float)h) * 4096.f);
        }
      }
      *(half8*)(h1s + ebase) = hi8;
      *(half8*)(h1s + PSTB + ebase) = lo8;
    }
    __syncthreads();
    // MFMA: unit = (single M-tile, single nt); wave parity pins nt
#pragma unroll 1
    for (int u = wv; u < 2 * MTB; u += 4) {
      const int mt = u >> 1;
      floatx16 accH = {}, accL = {};
      int px = mt * 32 + (lane & 31);
      px = px < LIMIT ? px : LIMIT - 1;
      const int r = px / S, cc = px - r * S;
      const int pixB = (r * SP + cc) * 16;
#pragma unroll 3
      for (int tap = 0; tap < 9; ++tap) {
        const int di = tap / 3, dj = tap - di * 3;
        const int offT = (di * SP + dj) * 16;
#pragma unroll
        for (int half = 0; half < 2; ++half) {
          const int ks = tap * 2 + half;
          const char* bp = bgbase + ks * 4096 + ntW * 1024;
          const int offA = pixB + offT + gOff + half * (2 * GSTB);
          half8 ah = *(const half8*)(h1s + offA);
          half8 al = *(const half8*)(h1s + PSTB + offA);
          half8 bh = *(const half8*)(bp);
          half8 bl = *(const half8*)(bp + 2048);
          accH = __builtin_amdgcn_mfma_f32_32x32x16_f16(ah, bh, accH, 0, 0, 0);
          accL = __builtin_amdgcn_mfma_f32_32x32x16_f16(ah, bl, accL, 0, 0, 0);
          accL = __builtin_amdgcn_mfma_f32_32x32x16_f16(al, bh, accL, 0, 0, 0);
        }
      }
#pragma unroll
      for (int reg = 0; reg < 16; ++reg) {
        int row = (reg & 3) + 8 * (reg >> 2) + 4 * (lane >> 5);
        int p = mt * 32 + row;
        if (p < LIMIT)
          sp += fmaxf(accH[reg] + accL[reg] * (1.f / 4096.f) + biasW, 0.f);
      }
    }
  }
  sp += __shfl_xor(sp, 32);
  if (lane < 32) featp[wv * 32 + lane] = sp;
  __syncthreads();
  if (t < 64) featp[t] = (featp[t] + featp[64 + t]) * (1.f / (S * S));
  __syncthreads();
  if (t < 64) {
    float s = 0.f;
#pragma unroll
    for (int i = 0; i < 64; ++i) s += featp[i] * fcw[t * 64 + i];
    zout[(size_t)b * 128 + zoff + t] = s + fcb[t];
  }
}

__global__ __launch_bounds__(256, 3) void encoders_fused(
    const float* __restrict__ x, const float* __restrict__ ce_w1,
    const float* __restrict__ ce_b1, const float* __restrict__ ce_b2,
    const float* __restrict__ ce_fcw, const float* __restrict__ ce_fcb,
    const float* __restrict__ ge_w1, const float* __restrict__ ge_b1,
    const float* __restrict__ ge_b2, const float* __restrict__ ge_fcw,
    const float* __restrict__ ge_fcb, const float* __restrict__ frags,
    float* __restrict__ z) {
  // S=28: 2*PSTB(46080) + xs(3600) + w1s(1152) + featp(512) = 51344
  __shared__ __align__(16) char smem[51344];
  if (blockIdx.x < 2048)
    encoder_body<28, false>(smem, x, ge_w1, ge_b1, ge_b2, ge_fcw, ge_fcb,
                            frags + 18432, z, 64, blockIdx.x);
  else
    encoder_body<14, true>(smem, x, ce_w1, ce_b1, ce_b2, ce_fcw, ce_fcb, frags,
                           z, 0, blockIdx.x - 2048);
}

// ---------------------------------------------------------------------------
// Kernel 3a: match via split-f16 MFMA.
// ---------------------------------------------------------------------------
__global__ __launch_bounds__(256) void match_mfma(
    const float* __restrict__ z, const float* __restrict__ memfrags,
    const float* __restrict__ invn, float* __restrict__ topvw,
    int* __restrict__ topiw) {
  __shared__ __align__(16) char smem[49408];
  float* zs = (float*)smem;            // [32][128] fp32 (staging)
  float* qv = (float*)smem;            // [32][128] (after zs dead)
  int* qi = (int*)(smem + 16384);      // [32][128]
  char* zfrag = smem + 32768;          // 16 KB: [p][ks][kg*32+m][16B]
  float* rowmin = (float*)(smem + 49152);
  int* qn = (int*)(smem + 49152 + 128);

  const int t = threadIdx.x;
  const int lane = t & 63;
  const int wv = t >> 6;
  const int rowbase = blockIdx.x * 32;
  const int Tbase = blockIdx.y * 16;

  for (int e = t; e < 4096; e += TPB) zs[e] = z[(size_t)rowbase * 128 + e];
  if (t < 32) { rowmin[t] = -FLT_MAX; qn[t] = 0; }
  __syncthreads();
#pragma unroll
  for (int h = 0; h < 8; ++h) {
    int r = wv * 8 + h;
    float a = zs[r * 128 + lane], b = zs[r * 128 + 64 + lane];
    float s = wave_reduce_sum(a * a + b * b);
    float inv = 1.f / fmaxf(sqrtf(s), 1e-12f);
    zs[r * 128 + lane] = a * inv;
    zs[r * 128 + 64 + lane] = b * inv;
  }
  __syncthreads();
  // build z A-fragments (2-part split), frag-major: entry (ks*64+kg*32+m)
  for (int e = t; e < 4096; e += TPB) {
    int m = e >> 7, c = e & 127;
    float v = zs[m * 128 + c];
    _Float16 h = (_Float16)v;
    _Float16 l = (_Float16)((v - (float)h) * 4096.f);
    int ks = c >> 4, kg = (c >> 3) & 1, j = c & 7;
    int off = (ks * 64 + kg * 32 + m) * 16 + j * 2;
    *(_Float16*)(zfrag + off) = h;
    *(_Float16*)(zfrag + 8192 + off) = l;
  }
  __syncthreads();

  // hoist A-fragments to registers (constant across all 16 n-tiles)
  half8 ah[8], al[8];
  {
    const char* zf = zfrag + ((lane >> 5) * 32 + (lane & 31)) * 16;
#pragma unroll
    for (int ks = 0; ks < 8; ++ks) {
      ah[ks] = *(const half8*)(zf + ks * 1024);
      al[ks] = *(const half8*)(zf + 8192 + ks * 1024);
    }
  }

  float av[10];
  int ai[10];
#pragma unroll
  for (int i = 0; i < 10; ++i) { av[i] = -FLT_MAX; ai[i] = 0; }

#pragma unroll 1
  for (int round = 0; round < 4; ++round) {
    const int T = Tbase + round * 4 + wv;
    const char* bf = (const char*)memfrags + (size_t)T * 16384 + lane * 16;
    floatx16 acc0 = {}, acc1 = {};
#pragma unroll
    for (int ks = 0; ks < 8; ++ks) {
      half8 bh = *(const half8*)(bf + ks * 1024);
      half8 bl = *(const half8*)(bf + 8192 + ks * 1024);
      acc0 = __builtin_amdgcn_mfma_f32_32x32x16_f16(ah[ks], bh, acc0, 0, 0, 0);
      acc1 = __builtin_amdgcn_mfma_f32_32x32x16_f16(ah[ks], bl, acc1, 0, 0, 0);
      acc1 = __builtin_amdgcn_mfma_f32_32x32x16_f16(al[ks], bh, acc1, 0, 0, 0);
    }
    const int gn = T * 32 + (lane & 31);
    const float iv = invn[gn];
#pragma unroll
    for (int reg = 0; reg < 16; ++reg) {
      int m = (reg & 3) + 8 * (reg >> 2) + 4 * (lane >> 5);
      float v = (acc0[reg] + acc1[reg] * (1.f / 4096.f)) * iv;
      if (v > rowmin[m]) {
        int k = atomicAdd(&qn[m], 1);
        qv[m * 128 + k] = v;
        qi[m * 128 + k] = gn;
      }
    }
    __syncthreads();
    if (t < 32) {
      int n = qn[t];
      for (int k = 0; k < n; ++k) {
        float v = qv[t * 128 + k];
        int mm = qi[t * 128 + k];
        if (v > av[9]) {
#pragma unroll
          for (int i = 0; i < 10; ++i) {
            if (v > av[i]) {
              float tv = av[i]; av[i] = v; v = tv;
              int ti = ai[i]; ai[i] = mm; mm = ti;
            }
          }
        }
      }
      qn[t] = 0;
      rowmin[t] = av[9];
    }
    __syncthreads();
  }

  if (t < 32) {
    const size_t base = (size_t)(rowbase + t) * 160 + blockIdx.y * 10;
#pragma unroll
    for (int k = 0; k < 10; ++k) {
      topvw[base + k] = av[k];
      topiw[base + k] = ai[k];
    }
  }
}

// ---------------------------------------------------------------------------
// Kernel 3b: merge 16x10 candidates -> exact top-10 -> softmax -> blend (f16).
// ---------------------------------------------------------------------------
__global__ __launch_bounds__(256) void match_merge(
    const float* __restrict__ topvw, const int* __restrict__ topiw,
    const float* __restrict__ memg, _Float16* __restrict__ zmf16) {
  __shared__ float topw[8][10];
  __shared__ int topidx[8][10];
  const int t = threadIdx.x;
  const int rowbase = blockIdx.x * 8;

  if (t < 8) {
    float av[10];
    int ai[10];
#pragma unroll
    for (int i = 0; i < 10; ++i) { av[i] = -FLT_MAX; ai[i] = 0; }
    const size_t base = (size_t)(rowbase + t) * 160;
    for (int c = 0; c < 160; ++c) {
      float v = topvw[base + c];
      int m = topiw[base + c];
      if (v > av[9]) {
#pragma unroll
        for (int i = 0; i < 10; ++i) {
          if (v > av[i]) {
            float tv = av[i]; av[i] = v; v = tv;
            int ti = ai[i]; ai[i] = m; m = ti;
          }
        }
      }
    }
    float e_[10], s = 0.f;
#pragma unroll
    for (int k = 0; k < 10; ++k) { e_[k] = expf(av[k]); s += e_[k]; }
    float inv = 1.f / s;
#pragma unroll
    for (int k = 0; k < 10; ++k) { topw[t][k] = e_[k] * inv; topidx[t][k] = ai[k]; }
  }
  __syncthreads();
  for (int e = t; e < 8 * 128; e += TPB) {
    int r = e >> 7, d = e & 127;
    float o = 0.f;
#pragma unroll
    for (int k = 0; k < 10; ++k)
      o += topw[r][k] * memg[(size_t)topidx[r][k] * 128 + d];
    zmf16[(size_t)(rowbase + r) * 128 + d] = (_Float16)o;
  }
}

// ---------------------------------------------------------------------------
// Kernel 4: decoder FC via f16 MFMA.
// ---------------------------------------------------------------------------
__global__ __launch_bounds__(256) void decfc_kernel(
    const _Float16* __restrict__ zmf16, const float* __restrict__ fcb,
    const float* __restrict__ dfcfrags, _Float16* __restrict__ d0f16) {
  const int t = threadIdx.x;
  const int lane = t & 63;
  const int wv = t >> 6;
  const int r0 = blockIdx.x * 32;
  const int ntbase = blockIdx.y * 49;

  half8 a[8];
  {
    const _Float16* ap =
        zmf16 + (size_t)(r0 + (lane & 31)) * 128 + (lane >> 5) * 8;
#pragma unroll
    for (int ks = 0; ks < 8; ++ks) a[ks] = *(const half8*)(ap + ks * 16);
  }
  const char* fb = (const char*)dfcfrags + lane * 16;

  for (int nt = ntbase + wv; nt < ntbase + 49; nt += 4) {
    half8 bfr[8];
    const char* p = fb + (size_t)nt * 8192;
#pragma unroll
    for (int ks = 0; ks < 8; ++ks) bfr[ks] = *(const half8*)(p + ks * 1024);
    floatx16 acc = {};
#pragma unroll
    for (int ks = 0; ks < 8; ++ks)
      acc = __builtin_amdgcn_mfma_f32_32x32x16_f16(a[ks], bfr[ks], acc, 0, 0, 0);
    const int col = nt * 32 + (lane & 31);
    const int px = col >> 6, c = col & 63;
    const float bias = fcb[c * 49 + px];
#pragma unroll
    for (int reg = 0; reg < 16; ++reg) {
      int row = (reg & 3) + 8 * (reg >> 2) + 4 * (lane >> 5);
      d0f16[((size_t)(r0 + row) * 49 + px) * 64 + c] = (_Float16)(acc[reg] + bias);
    }
  }
}

// ---------------------------------------------------------------------------
// Kernel 5: decoder v4 — deconv1 + conv2 via f16 MFMA.
// ---------------------------------------------------------------------------
__global__ __launch_bounds__(256) void decoder_kernel(
    const _Float16* __restrict__ d0f16, const float* __restrict__ b1,
    const float* __restrict__ w2, const float* __restrict__ b2,
    const float* __restrict__ w3, const float* __restrict__ b3,
    const float* __restrict__ w4, const float* __restrict__ b4,
    const float* __restrict__ dec1frags, float* __restrict__ out) {
  __shared__ __align__(16) char dsm[41408];
  char* d0f = dsm;
  float* d2 = (float*)dsm;
  char* d1f = dsm + 12608;
  char* w2s = dsm + 28992;
  float* d3 = (float*)(dsm + 12608);

  const int b = blockIdx.x;
  const int t = threadIdx.x;
  const int lane = t & 63;
  const int wv = t >> 6;

  for (int e = t; e < 648; e += TPB) {
    int g = e / 81, pix = e - g * 81;
    int ih = pix / 9 - 1, iw = pix % 9 - 1;
    half8 hv = {};
    if (ih >= 0 && ih < 7 && iw >= 0 && iw < 7)
      hv = *(const half8*)(d0f16 + ((size_t)b * 49 + ih * 7 + iw) * 64 + g * 8);
    *(half8*)(d0f + e * 16) = hv;
  }
  for (int e = t; e < 576; e += TPB) {
    int tau = e / 64, l = e - tau * 64;
    int n = l & 15, kq = l >> 4;
    half8 v;
#pragma unroll
    for (int u = 0; u < 8; ++u)
      v[u] = (_Float16)w2[(n * 32 + kq * 8 + u) * 9 + tau];
    *(half8*)(w2s + e * 16) = v;
  }
  for (int e = t; e < 1024; e += TPB)
    *(float4*)(d1f + e * 16) = make_float4(0.f, 0.f, 0.f, 0.f);
  __syncthreads();

  {
    const int pa = wv >> 1, pb = wv & 1;
    const int kg = lane >> 5, o = lane & 31;
    const char* bg = (const char*)dec1frags + wv * 16384 + lane * 16;
    int pxa[2][4];
#pragma unroll
    for (int im = 0; im < 2; ++im) {
      int px = im * 32 + o;
      px = px < 49 ? px : 48;
      int i = px / 7, j2 = px - i * 7;
#pragma unroll
      for (int st = 0; st < 4; ++st) {
        int s = st >> 1, tt = st & 1;
        pxa[im][st] = ((i + pa + s) * 9 + (j2 + pb + tt)) * 16;
      }
    }
    floatx16 acc0 = {}, acc1 = {};
    half8 nb = *(const half8*)(bg);
#pragma unroll
    for (int ks = 0; ks < 16; ++ks) {
      half8 bf = nb;
      if (ks < 15) nb = *(const half8*)(bg + (ks + 1) * 1024);
      const int gbase = (((ks & 3) * 2 + kg) * 81) * 16;
      half8 a0 = *(const half8*)(d0f + gbase + pxa[0][ks >> 2]);
      half8 a1 = *(const half8*)(d0f + gbase + pxa[1][ks >> 2]);
      acc0 = __builtin_amdgcn_mfma_f32_32x32x16_f16(a0, bf, acc0, 0, 0, 0);
      acc1 = __builtin_amdgcn_mfma_f32_32x32x16_f16(a1, bf, acc1, 0, 0, 0);
    }
    const float bias = b1[o];
    char* dst = d1f + (o >> 3) * 4096 + (o & 7) * 2;
#pragma unroll
    for (int im = 0; im < 2; ++im) {
      const floatx16& ac = im ? acc1 : acc0;
#pragma unroll
      for (int reg = 0; reg < 16; ++reg) {
        int row = (reg & 3) + 8 * (reg >> 2) + 4 * kg;
        int px = im * 32 + row;
        if (px < 49) {
          int i = px / 7, j2 = px - i * 7;
          int p = 2 * i + pa, q = 2 * j2 + pb;
          *(_Float16*)(dst + ((p + 1) * 16 + (q + 1)) * 16) =
              (_Float16)fmaxf(ac[reg] + bias, 0.f);
        }
      }
    }
  }
  __syncthreads();

  {
    const int m = lane & 15, kq = lane >> 4;
    half8 bq[9];
#pragma unroll
    for (int tau = 0; tau < 9; ++tau)
      bq[tau] = *(const half8*)(w2s + (tau * 64 + lane) * 16);
    for (int mt = wv; mt < 13; mt += 4) {
      int px = mt * 16 + m;
      px = px < 196 ? px : 195;
      const int p = px / 14, q = px - (px / 14) * 14;
      floatx4 acc = {};
#pragma unroll
      for (int tau = 0; tau < 9; ++tau) {
        const int dp = tau / 3, dq = tau - dp * 3;
        half8 av =
            *(const half8*)(d1f + (kq * 256 + (p + dp) * 16 + (q + dq)) * 16);
        acc = __builtin_amdgcn_mfma_f32_16x16x32_f16(av, bq[tau], acc, 0, 0, 0);
      }
      const int o = lane & 15;
      const float bias = b2[o];
#pragma unroll
      for (int reg = 0; reg < 4; ++reg) {
        int row = (lane >> 4) * 4 + reg;
        int opx = mt * 16 + row;
        if (opx < 196) d2[o * 197 + opx] = fmaxf(acc[reg] + bias, 0.f);
      }
    }
  }
  __syncthreads();
  for (int e = t; e < 7200; e += TPB) d3[e] = 0.f;
  __syncthreads();

  {
    const int ph = __builtin_amdgcn_readfirstlane(t >> 6);
    const int pa = ph >> 1, pb = ph & 1;
    const int tb = pa * 4 + pb;
    const float* wA = w3 + (size_t)tb * 128;
    const float* wB = w3 + (size_t)(tb + 2) * 128;
    const float* wC = w3 + (size_t)(tb + 8) * 128;
    const float* wD = w3 + (size_t)(tb + 10) * 128;
#pragma unroll 1
    for (int k = 0; k < 4; ++k) {
      const int px = lane + 64 * k;
      const int cpx = px < 196 ? px : 195;
      const int i = cpx / 14, j = cpx % 14;
      int ih[2], iw[2];
      float mh[2], mw[2];
#pragma unroll
      for (int s = 0; s < 2; ++s) {
        int v = i + pa + s - 1;
        mh[s] = (v >= 0 && v <= 13) ? 1.f : 0.f;
        ih[s] = v < 0 ? 0 : (v > 13 ? 13 : v);
        int u = j + pb + s - 1;
        mw[s] = (u >= 0 && u <= 13) ? 1.f : 0.f;
        iw[s] = u < 0 ? 0 : (u > 13 ? 13 : u);
      }
      const float m00 = mh[0] * mw[0], m01 = mh[0] * mw[1];
      const float m10 = mh[1] * mw[0], m11 = mh[1] * mw[1];
      float acc[8];
#pragma unroll
      for (int oo = 0; oo < 8; ++oo) acc[oo] = b3[oo];
#pragma unroll 2
      for (int c = 0; c < 16; ++c) {
        const float a00 = d2[c * 197 + ih[0] * 14 + iw[0]] * m00;
        const float a01 = d2[c * 197 + ih[0] * 14 + iw[1]] * m01;
        const float a10 = d2[c * 197 + ih[1] * 14 + iw[0]] * m10;
        const float a11 = d2[c * 197 + ih[1] * 14 + iw[1]] * m11;
        const int wb = c * 8;
#pragma unroll
        for (int oo = 0; oo < 8; ++oo)
          acc[oo] += a00 * wA[wb + oo] + a01 * wB[wb + oo] +
                     a10 * wC[wb + oo] + a11 * wD[wb + oo];
      }
      if (px < 196) {
        const int p = 2 * i + pa, q = 2 * j + pb;
        const int widx = (p + 1) * 30 + (q + 1);
#pragma unroll
        for (int oo = 0; oo < 8; ++oo)
          d3[oo * 900 + widx] = fmaxf(acc[oo], 0.f);
      }
    }
  }
  __syncthreads();

  for (int e = t; e < 784; e += TPB) {
    int p = e / 28, q = e - p * 28;
    float a = b4[0];
#pragma unroll
    for (int c = 0; c < 8; ++c) {
      const float* bp = &d3[c * 900 + p * 30 + q];
#pragma unroll
      for (int di = 0; di < 3; ++di)
#pragma unroll
        for (int dj = 0; dj < 3; ++dj)
          a += bp[di * 30 + dj] * w4[c * 9 + di * 3 + dj];
    }
    out[(size_t)b * 784 + e] = a;
  }
}

// ---------------------------------------------------------------------------
extern "C" void kernel_launch(void* const* d_in, const int* in_sizes, int n_in,
                              void* d_out, int out_size, void* d_ws,
                              size_t ws_size, hipStream_t stream) {
  const float* x      = (const float*)d_in[0];
  const float* ce_w1  = (const float*)d_in[1];
  const float* ce_b1  = (const float*)d_in[2];
  const float* ce_w2  = (const float*)d_in[3];
  const float* ce_b2  = (const float*)d_in[4];
  const float* ce_fcw = (const float*)d_in[5];
  const float* ce_fcb = (const float*)d_in[6];
  const float* ge_w1  = (const float*)d_in[7];
  const float* ge_b1  = (const float*)d_in[8];
  const float* ge_w2  = (const float*)d_in[9];
  const float* ge_b2  = (const float*)d_in[10];
  const float* ge_fcw = (const float*)d_in[11];
  const float* ge_fcb = (const float*)d_in[12];
  const float* memg   = (const float*)d_in[13];
  const float* dfcw   = (const float*)d_in[14];
  const float* dfcb   = (const float*)d_in[15];
  const float* d_w1   = (const float*)d_in[16];
  const float* d_b1   = (const float*)d_in[17];
  const float* d_w2   = (const float*)d_in[18];
  const float* d_b2   = (const float*)d_in[19];
  const float* d_w3   = (const float*)d_in[20];
  const float* d_b3   = (const float*)d_in[21];
  const float* d_w4   = (const float*)d_in[22];
  const float* d_b4   = (const float*)d_in[23];
  float* outp = (float*)d_out;

  float*     ws        = (float*)d_ws;
  float*     z         = ws;
  _Float16*  zmf16     = (_Float16*)(ws + 262144);
  float*     invn      = ws + 262144 + 131072;
  float*     frags     = invn + 8192;
  float*     dec1frags = frags + 36864;
  float*     dfcfrags  = dec1frags + 16384;
  float*     memfrags  = dfcfrags + 200704;
  float*     tailbase  = memfrags + 1048576;
  float*     topvw     = tailbase;
  int*       topiw     = (int*)(tailbase + 327680);
  _Float16*  d0f16     = (_Float16*)tailbase;

  prep_bfrags<<<144, 64, 0, stream>>>(ce_w2, ge_w2, frags);
  prep_dec1<<<64, 64, 0, stream>>>(d_w1, dec1frags);
  prep_dfc<<<784, 64, 0, stream>>>(dfcw, dfcfrags);
  prep_mem<<<4096, 64, 0, stream>>>(memg, memfrags);
  norm_kernel<<<2048, TPB, 0, stream>>>(memg, invn);
  encoders_fused<<<4096, TPB, 0, stream>>>(x, ce_w1, ce_b1, ce_b2, ce_fcw,
                                           ce_fcb, ge_w1, ge_b1, ge_b2, ge_fcw,
                                           ge_fcb, frags, z);
  match_mfma<<<dim3(64, 16), TPB, 0, stream>>>(z, memfrags, invn, topvw, topiw);
  match_merge<<<256, TPB, 0, stream>>>(topvw, topiw, memg, zmf16);
  decfc_kernel<<<dim3(64, 2), TPB, 0, stream>>>(zmf16, dfcb, dfcfrags, d0f16);
  decoder_kernel<<<2048, TPB, 0, stream>>>(d0f16, d_b1, d_w2, d_b2, d_w3, d_b3,
                                           d_w4, d_b4, dec1frags, outp);
}